// Round 11
// baseline (108.085 us; speedup 1.0000x reference)
//
#include <hip/hip_runtime.h>

// Problem constants (fixed by the reference file): B=8, N=4096.
#define NN 4096
#define BB 8
#define JT 4          // ISNet rows per block
#define KS 2          // k-splits
#define KH (NN / KS)  // 2048 k per block

// Main kernel: grid (NN/JT)*KS = 2048 blocks x 256 threads (4 waves).
// Block (jb,ks): rows j0..j0+3, k-half ks. Wave w owns batches {2w,2w+1}
// -> EXACTLY the R6 per-wave structure (56 VGPR, zero spill, no barriers),
// just half the k-range, so the grid doubles: 8 blocks/CU -> up to 32
// waves/CU (R6 was grid-limited to 16). Traffic unchanged (384 MB); this
// round isolates latency-hiding from bandwidth.
// R7/R10 lesson: >2-batch tiles or LDS staging make the allocator spill
// (64 VGPR + 35-80 MB scratch) - stay at JT=4/BT=2.
// Factor math identical to the R4/6 passing scheme; reduction is the
// verified 3-xor + select + 3-down; partials -> d_ws, combine verified R9.

__device__ __forceinline__ float2 pk_mul(float2 a, float2 b) {
    return make_float2(a.x * b.x, a.y * b.y);
}
__device__ __forceinline__ float2 pk_add(float2 a, float2 b) {
    return make_float2(a.x + b.x, a.y + b.y);
}
__device__ __forceinline__ float2 pk_fnma(float2 a, float2 b, float2 c) {  // c - a*b
    return make_float2(fmaf(-a.x, b.x, c.x), fmaf(-a.y, b.y, c.y));
}

__global__ __launch_bounds__(256, 8) void epi_partial(
    const float* __restrict__ state,    // [B,4,N]
    const float* __restrict__ ISNet,    // [N,N]
    const float* __restrict__ psMatrix, // [4,4]
    double* __restrict__ ws)            // [KS,BB,NN] partial products
{
    const int ks   = blockIdx.x & (KS - 1);
    const int jb   = blockIdx.x >> 1;
    const int j0   = jb * JT;
    const int tid  = threadIdx.x;
    const int wave = tid >> 6;
    const int lane = tid & 63;
    const int b0   = wave * 2;          // this wave's two batches
    const int kb   = ks * KH;

    const float p01 = psMatrix[1];      // psM[0,1] == psMatrix[0,1]

    float  cf[JT][2];
    double prod[JT][2];
    #pragma unroll
    for (int jj = 0; jj < JT; ++jj) {
        #pragma unroll
        for (int bi = 0; bi < 2; ++bi) {
            cf[jj][bi]   = state[(size_t)(b0 + bi) * 4 * NN + (j0 + jj)] * p01;
            prod[jj][bi] = 1.0;
        }
    }

    const float4* __restrict__ w0 = (const float4*)(ISNet + (size_t)(j0 + 0) * NN + kb);
    const float4* __restrict__ w1 = (const float4*)(ISNet + (size_t)(j0 + 1) * NN + kb);
    const float4* __restrict__ w2 = (const float4*)(ISNet + (size_t)(j0 + 2) * NN + kb);
    const float4* __restrict__ w3 = (const float4*)(ISNet + (size_t)(j0 + 3) * NN + kb);
    const float4* __restrict__ i0 = (const float4*)(state + ((size_t)(b0 + 0) * 4 + 2) * NN + kb);
    const float4* __restrict__ i1 = (const float4*)(state + ((size_t)(b0 + 1) * 4 + 2) * NN + kb);

    float4 wA[JT], wB[JT], wC[JT], ia[2], ib[2];

#define LW(BUF, IDX) do { const int _x = lane + (IDX) * 64; \
        BUF[0] = w0[_x]; BUF[1] = w1[_x]; BUF[2] = w2[_x]; BUF[3] = w3[_x]; } while (0)
#define LI(BUF, IDX) do { const int _x = lane + (IDX) * 64; \
        BUF[0] = i0[_x]; BUF[1] = i1[_x]; } while (0)

    auto compute = [&](const float4 (&W)[JT], const float4 (&I)[2]) {
        #pragma unroll
        for (int jj = 0; jj < JT; ++jj) {
            const float2 w01 = make_float2(W[jj].x, W[jj].y);
            const float2 w23 = make_float2(W[jj].z, W[jj].w);
            #pragma unroll
            for (int bi = 0; bi < 2; ++bi) {
                const float4& I4 = bi ? I[1] : I[0];
                const float2 c2  = make_float2(cf[jj][bi], cf[jj][bi]);
                const float2 z01 = pk_mul(pk_mul(c2, w01), make_float2(I4.x, I4.y));
                const float2 z23 = pk_mul(pk_mul(c2, w23), make_float2(I4.z, I4.w));
                const float2 q2  = pk_fnma(z01, z23, pk_add(z01, z23));
                const float  q   = fmaf(-q2.x, q2.y, q2.x + q2.y);
                prod[jj][bi] = fma(-(double)q, prod[jj][bi], prod[jj][bi]);
            }
        }
    };

    // 8 stages (KH/256 k per stage); w triple-buffered (dist 3), I double (dist 2).
#define STEP(W, I, K) do { compute(W, I); \
        if ((K) + 3 < 8) LW(W, (K) + 3); if ((K) + 2 < 8) LI(I, (K) + 2); } while (0)

    LW(wA, 0); LI(ia, 0); LW(wB, 1); LI(ib, 1); LW(wC, 2);
    STEP(wA, ia, 0); STEP(wB, ib, 1); STEP(wC, ia, 2); STEP(wA, ib, 3);
    STEP(wB, ia, 4); STEP(wC, ib, 5); STEP(wA, ia, 6); STEP(wB, ib, 7);
#undef STEP
#undef LW
#undef LI

    // 3 XOR-butterfly levels -> every lane holds its mod-8 residue partial.
    #pragma unroll
    for (int off = 32; off >= 8; off >>= 1) {
        #pragma unroll
        for (int jj = 0; jj < JT; ++jj) {
            #pragma unroll
            for (int bi = 0; bi < 2; ++bi)
                prod[jj][bi] *= __shfl_xor(prod[jj][bi], off, 64);
        }
    }

    // 8-lane group g reduces pair g = (jj<<1)|bi.
    const int g = lane >> 3;
    double v = prod[0][0];
    v = (g == 1) ? prod[0][1] : v; v = (g == 2) ? prod[1][0] : v;
    v = (g == 3) ? prod[1][1] : v; v = (g == 4) ? prod[2][0] : v;
    v = (g == 5) ? prod[2][1] : v; v = (g == 6) ? prod[3][0] : v;
    v = (g == 7) ? prod[3][1] : v;
    v *= __shfl_down(v, 4, 64);
    v *= __shfl_down(v, 2, 64);
    v *= __shfl_down(v, 1, 64);

    if ((lane & 7) == 0) {              // pair g: j = j0+(g>>1), b = b0+(g&1)
        const int j = j0 + (g >> 1);
        const int b = b0 + (g & 1);
        ws[((size_t)ks * BB + b) * NN + j] = v;
    }
}

// Combine: tot = ws[0][b][j] * ws[1][b][j]; 4x4 mix + sampling epilogue.
// 32768 threads, fully coalesced over j.  (Verified in rounds 9/10.)
__global__ __launch_bounds__(256) void epi_combine(
    const float* __restrict__ state,    // [B,4,N]
    const float* __restrict__ psMatrix, // [4,4]
    const float* __restrict__ U,        // [N]
    const double* __restrict__ ws,      // [KS,BB,NN]
    float* __restrict__ out)            // [B,4,N]
{
    const int p = blockIdx.x * 256 + threadIdx.x;   // 0 .. BB*NN-1
    const int b = p >> 12;              // NN = 4096 = 2^12
    const int j = p & (NN - 1);

    const double tot = ws[(size_t)b * NN + j] * ws[((size_t)BB * NN) + (size_t)b * NN + j];
    const double ps1 = 1.0 - tot;

    // expand_psMatrix in f64
    double pm[4][4];
    #pragma unroll
    for (int r = 0; r < 4; ++r) {
        double s = 0.0;
        #pragma unroll
        for (int q = 0; q < 4; ++q) {
            pm[r][q] = (double)psMatrix[r * 4 + q];
            s += pm[r][q];
        }
        pm[r][r] += (1.0 - s);
    }

    double st[4];
    #pragma unroll
    for (int r = 0; r < 4; ++r)
        st[r] = (double)state[(size_t)b * 4 * NN + r * NN + j];

    const double S = st[0];
    const double ps10[4] = {1.0 - ps1, ps1, 0.0, 0.0};

    double P[4];
    #pragma unroll
    for (int i = 0; i < 4; ++i) {
        double acc = S * ps10[i];
        #pragma unroll
        for (int r = 1; r < 4; ++r)
            acc += pm[r][i] * st[r];
        P[i] = acc;
    }

    double u = (double)U[j];
    #pragma unroll
    for (int i = 0; i < 4; ++i) {
        u -= P[i];
        const double s = (u < 0.0) ? 1.0 : 0.0;
        out[(size_t)b * 4 * NN + i * NN + j] = (float)s;
        u += s;
    }
}

// ---------- Fallback (verbatim round-6 kernel, used only if ws too small) ----------
__global__ __launch_bounds__(256, 4) void epi_fallback(
    const float* __restrict__ state, const float* __restrict__ ISNet,
    const float* __restrict__ psMatrix, const float* __restrict__ U,
    float* __restrict__ out)
{
    const int j0 = blockIdx.x * JT;
    const int tid = threadIdx.x;
    const int wave = tid >> 6, lane = tid & 63;
    const int b0 = wave * 2;
    const float p01 = psMatrix[1];
    float cf[JT][2]; double prod[JT][2];
    #pragma unroll
    for (int jj = 0; jj < JT; ++jj)
        #pragma unroll
        for (int bi = 0; bi < 2; ++bi) {
            cf[jj][bi] = state[(size_t)(b0 + bi) * 4 * NN + (j0 + jj)] * p01;
            prod[jj][bi] = 1.0;
        }
    const float4* __restrict__ w0 = (const float4*)(ISNet + (size_t)(j0 + 0) * NN);
    const float4* __restrict__ w1 = (const float4*)(ISNet + (size_t)(j0 + 1) * NN);
    const float4* __restrict__ w2 = (const float4*)(ISNet + (size_t)(j0 + 2) * NN);
    const float4* __restrict__ w3 = (const float4*)(ISNet + (size_t)(j0 + 3) * NN);
    const float4* __restrict__ i0 = (const float4*)(state + ((size_t)(b0 + 0) * 4 + 2) * NN);
    const float4* __restrict__ i1 = (const float4*)(state + ((size_t)(b0 + 1) * 4 + 2) * NN);
    float4 wA[JT], wB[JT], wC[JT], ia[2], ib[2];
#define LW(BUF, IDX) do { const int _x = lane + (IDX) * 64; \
        BUF[0] = w0[_x]; BUF[1] = w1[_x]; BUF[2] = w2[_x]; BUF[3] = w3[_x]; } while (0)
#define LI(BUF, IDX) do { const int _x = lane + (IDX) * 64; \
        BUF[0] = i0[_x]; BUF[1] = i1[_x]; } while (0)
    auto compute = [&](const float4 (&W)[JT], const float4 (&I)[2]) {
        #pragma unroll
        for (int jj = 0; jj < JT; ++jj) {
            const float2 w01 = make_float2(W[jj].x, W[jj].y);
            const float2 w23 = make_float2(W[jj].z, W[jj].w);
            #pragma unroll
            for (int bi = 0; bi < 2; ++bi) {
                const float4& I4 = bi ? I[1] : I[0];
                const float2 c2 = make_float2(cf[jj][bi], cf[jj][bi]);
                const float2 z01 = pk_mul(pk_mul(c2, w01), make_float2(I4.x, I4.y));
                const float2 z23 = pk_mul(pk_mul(c2, w23), make_float2(I4.z, I4.w));
                const float2 q2 = pk_fnma(z01, z23, pk_add(z01, z23));
                const float q = fmaf(-q2.x, q2.y, q2.x + q2.y);
                prod[jj][bi] = fma(-(double)q, prod[jj][bi], prod[jj][bi]);
            }
        }
    };
#define STEP(W, I, K) do { compute(W, I); \
        if ((K) + 3 < 16) LW(W, (K) + 3); if ((K) + 2 < 16) LI(I, (K) + 2); } while (0)
    LW(wA, 0); LI(ia, 0); LW(wB, 1); LI(ib, 1); LW(wC, 2);
    STEP(wA, ia, 0);  STEP(wB, ib, 1);  STEP(wC, ia, 2);  STEP(wA, ib, 3);
    STEP(wB, ia, 4);  STEP(wC, ib, 5);  STEP(wA, ia, 6);  STEP(wB, ib, 7);
    STEP(wC, ia, 8);  STEP(wA, ib, 9);  STEP(wB, ia, 10); STEP(wC, ib, 11);
    STEP(wA, ia, 12); STEP(wB, ib, 13); STEP(wC, ia, 14); STEP(wA, ib, 15);
#undef STEP
#undef LW
#undef LI
    #pragma unroll
    for (int off = 32; off >= 8; off >>= 1)
        #pragma unroll
        for (int jj = 0; jj < JT; ++jj)
            #pragma unroll
            for (int bi = 0; bi < 2; ++bi)
                prod[jj][bi] *= __shfl_xor(prod[jj][bi], off, 64);
    const int g = lane >> 3;
    double v = prod[0][0];
    v = (g == 1) ? prod[0][1] : v; v = (g == 2) ? prod[1][0] : v;
    v = (g == 3) ? prod[1][1] : v; v = (g == 4) ? prod[2][0] : v;
    v = (g == 5) ? prod[2][1] : v; v = (g == 6) ? prod[3][0] : v;
    v = (g == 7) ? prod[3][1] : v;
    v *= __shfl_down(v, 4, 64); v *= __shfl_down(v, 2, 64); v *= __shfl_down(v, 1, 64);
    __shared__ double red[JT][BB];
    if ((lane & 7) == 0) red[g >> 1][b0 + (g & 1)] = v;
    __syncthreads();
    if (tid < JT * BB) {
        const int jj = tid >> 3, b = tid & 7;
        const int j = j0 + jj;
        const double ps1 = 1.0 - red[jj][b];
        double pm[4][4];
        #pragma unroll
        for (int r = 0; r < 4; ++r) {
            double s = 0.0;
            #pragma unroll
            for (int q = 0; q < 4; ++q) { pm[r][q] = (double)psMatrix[r * 4 + q]; s += pm[r][q]; }
            pm[r][r] += (1.0 - s);
        }
        double st[4];
        #pragma unroll
        for (int r = 0; r < 4; ++r) st[r] = (double)state[(size_t)b * 4 * NN + r * NN + j];
        const double S = st[0];
        const double ps10[4] = {1.0 - ps1, ps1, 0.0, 0.0};
        double P[4];
        #pragma unroll
        for (int i = 0; i < 4; ++i) {
            double acc = S * ps10[i];
            #pragma unroll
            for (int r = 1; r < 4; ++r) acc += pm[r][i] * st[r];
            P[i] = acc;
        }
        double u = (double)U[j];
        #pragma unroll
        for (int i = 0; i < 4; ++i) {
            u -= P[i];
            const double s = (u < 0.0) ? 1.0 : 0.0;
            out[(size_t)b * 4 * NN + i * NN + j] = (float)s;
            u += s;
        }
    }
}

extern "C" void kernel_launch(void* const* d_in, const int* in_sizes, int n_in,
                              void* d_out, int out_size, void* d_ws, size_t ws_size,
                              hipStream_t stream) {
    const float* state    = (const float*)d_in[0];  // [8,4,4096]
    const float* ISNet    = (const float*)d_in[1];  // [4096,4096]
    const float* psMatrix = (const float*)d_in[2];  // [4,4]
    const float* U        = (const float*)d_in[3];  // [4096]
    float* out            = (float*)d_out;          // [8,4,4096]

    const size_t need = (size_t)KS * BB * NN * sizeof(double);  // 512 KB
    if (ws_size >= need) {
        double* ws = (double*)d_ws;
        epi_partial<<<(NN / JT) * KS, 256, 0, stream>>>(state, ISNet, psMatrix, ws);
        epi_combine<<<(BB * NN) / 256, 256, 0, stream>>>(state, psMatrix, U, ws, out);
    } else {
        epi_fallback<<<NN / JT, 256, 0, stream>>>(state, ISNet, psMatrix, U, out);
    }
}

// Round 12
// 25.553 us; speedup vs baseline: 4.2299x; 4.2299x over previous
//
#include <hip/hip_runtime.h>

// Problem constants (fixed by the reference file): B=8, N=4096.
#define NN 4096
#define BB 8
#define JT 4          // ISNet rows per block
#define KS 2          // k-splits
#define KH (NN / KS)  // 2048 k per block

// Main kernel: grid (NN/JT)*KS = 2048 blocks x 256 threads (4 waves).
// Block (jb,ks): rows j0..j0+3, k-half ks. Wave w owns batches {2w,2w+1}
// -> EXACTLY the R6 per-wave structure (56 VGPR, zero spill, no barriers),
// half the k-range, doubled grid: 8 blocks/CU -> up to 32 waves/CU
// (R6 was grid-limited to 16). Traffic unchanged (384 MB).
// R11 lesson: __launch_bounds__(256,8) cut the VGPR budget to 64, the
// allocator collapsed to 32 VGPR + 292 MB scratch. Keep (256,4): the
// compiler emits ~56 VGPR and the HARDWARE still fits 8 blocks/CU.
// Factor math identical to the R4/6 passing scheme; reduction is the
// verified 3-xor + select + 3-down; partials -> d_ws, combine verified R9.

__device__ __forceinline__ float2 pk_mul(float2 a, float2 b) {
    return make_float2(a.x * b.x, a.y * b.y);
}
__device__ __forceinline__ float2 pk_add(float2 a, float2 b) {
    return make_float2(a.x + b.x, a.y + b.y);
}
__device__ __forceinline__ float2 pk_fnma(float2 a, float2 b, float2 c) {  // c - a*b
    return make_float2(fmaf(-a.x, b.x, c.x), fmaf(-a.y, b.y, c.y));
}

__global__ __launch_bounds__(256, 4) void epi_partial(
    const float* __restrict__ state,    // [B,4,N]
    const float* __restrict__ ISNet,    // [N,N]
    const float* __restrict__ psMatrix, // [4,4]
    double* __restrict__ ws)            // [KS,BB,NN] partial products
{
    const int ks   = blockIdx.x & (KS - 1);
    const int jb   = blockIdx.x >> 1;
    const int j0   = jb * JT;
    const int tid  = threadIdx.x;
    const int wave = tid >> 6;
    const int lane = tid & 63;
    const int b0   = wave * 2;          // this wave's two batches
    const int kb   = ks * KH;

    const float p01 = psMatrix[1];      // psM[0,1] == psMatrix[0,1]

    float  cf[JT][2];
    double prod[JT][2];
    #pragma unroll
    for (int jj = 0; jj < JT; ++jj) {
        #pragma unroll
        for (int bi = 0; bi < 2; ++bi) {
            cf[jj][bi]   = state[(size_t)(b0 + bi) * 4 * NN + (j0 + jj)] * p01;
            prod[jj][bi] = 1.0;
        }
    }

    const float4* __restrict__ w0 = (const float4*)(ISNet + (size_t)(j0 + 0) * NN + kb);
    const float4* __restrict__ w1 = (const float4*)(ISNet + (size_t)(j0 + 1) * NN + kb);
    const float4* __restrict__ w2 = (const float4*)(ISNet + (size_t)(j0 + 2) * NN + kb);
    const float4* __restrict__ w3 = (const float4*)(ISNet + (size_t)(j0 + 3) * NN + kb);
    const float4* __restrict__ i0 = (const float4*)(state + ((size_t)(b0 + 0) * 4 + 2) * NN + kb);
    const float4* __restrict__ i1 = (const float4*)(state + ((size_t)(b0 + 1) * 4 + 2) * NN + kb);

    float4 wA[JT], wB[JT], wC[JT], ia[2], ib[2];

#define LW(BUF, IDX) do { const int _x = lane + (IDX) * 64; \
        BUF[0] = w0[_x]; BUF[1] = w1[_x]; BUF[2] = w2[_x]; BUF[3] = w3[_x]; } while (0)
#define LI(BUF, IDX) do { const int _x = lane + (IDX) * 64; \
        BUF[0] = i0[_x]; BUF[1] = i1[_x]; } while (0)

    auto compute = [&](const float4 (&W)[JT], const float4 (&I)[2]) {
        #pragma unroll
        for (int jj = 0; jj < JT; ++jj) {
            const float2 w01 = make_float2(W[jj].x, W[jj].y);
            const float2 w23 = make_float2(W[jj].z, W[jj].w);
            #pragma unroll
            for (int bi = 0; bi < 2; ++bi) {
                const float4& I4 = bi ? I[1] : I[0];
                const float2 c2  = make_float2(cf[jj][bi], cf[jj][bi]);
                const float2 z01 = pk_mul(pk_mul(c2, w01), make_float2(I4.x, I4.y));
                const float2 z23 = pk_mul(pk_mul(c2, w23), make_float2(I4.z, I4.w));
                const float2 q2  = pk_fnma(z01, z23, pk_add(z01, z23));
                const float  q   = fmaf(-q2.x, q2.y, q2.x + q2.y);
                prod[jj][bi] = fma(-(double)q, prod[jj][bi], prod[jj][bi]);
            }
        }
    };

    // 8 stages (KH/256 k per stage); w triple-buffered (dist 3), I double (dist 2).
#define STEP(W, I, K) do { compute(W, I); \
        if ((K) + 3 < 8) LW(W, (K) + 3); if ((K) + 2 < 8) LI(I, (K) + 2); } while (0)

    LW(wA, 0); LI(ia, 0); LW(wB, 1); LI(ib, 1); LW(wC, 2);
    STEP(wA, ia, 0); STEP(wB, ib, 1); STEP(wC, ia, 2); STEP(wA, ib, 3);
    STEP(wB, ia, 4); STEP(wC, ib, 5); STEP(wA, ia, 6); STEP(wB, ib, 7);
#undef STEP
#undef LW
#undef LI

    // 3 XOR-butterfly levels -> every lane holds its mod-8 residue partial.
    #pragma unroll
    for (int off = 32; off >= 8; off >>= 1) {
        #pragma unroll
        for (int jj = 0; jj < JT; ++jj) {
            #pragma unroll
            for (int bi = 0; bi < 2; ++bi)
                prod[jj][bi] *= __shfl_xor(prod[jj][bi], off, 64);
        }
    }

    // 8-lane group g reduces pair g = (jj<<1)|bi.
    const int g = lane >> 3;
    double v = prod[0][0];
    v = (g == 1) ? prod[0][1] : v; v = (g == 2) ? prod[1][0] : v;
    v = (g == 3) ? prod[1][1] : v; v = (g == 4) ? prod[2][0] : v;
    v = (g == 5) ? prod[2][1] : v; v = (g == 6) ? prod[3][0] : v;
    v = (g == 7) ? prod[3][1] : v;
    v *= __shfl_down(v, 4, 64);
    v *= __shfl_down(v, 2, 64);
    v *= __shfl_down(v, 1, 64);

    if ((lane & 7) == 0) {              // pair g: j = j0+(g>>1), b = b0+(g&1)
        const int j = j0 + (g >> 1);
        const int b = b0 + (g & 1);
        ws[((size_t)ks * BB + b) * NN + j] = v;
    }
}

// Combine: tot = ws[0][b][j] * ws[1][b][j]; 4x4 mix + sampling epilogue.
// 32768 threads, fully coalesced over j.  (Verified in rounds 9/10.)
__global__ __launch_bounds__(256) void epi_combine(
    const float* __restrict__ state,    // [B,4,N]
    const float* __restrict__ psMatrix, // [4,4]
    const float* __restrict__ U,        // [N]
    const double* __restrict__ ws,      // [KS,BB,NN]
    float* __restrict__ out)            // [B,4,N]
{
    const int p = blockIdx.x * 256 + threadIdx.x;   // 0 .. BB*NN-1
    const int b = p >> 12;              // NN = 4096 = 2^12
    const int j = p & (NN - 1);

    const double tot = ws[(size_t)b * NN + j] * ws[((size_t)BB * NN) + (size_t)b * NN + j];
    const double ps1 = 1.0 - tot;

    // expand_psMatrix in f64
    double pm[4][4];
    #pragma unroll
    for (int r = 0; r < 4; ++r) {
        double s = 0.0;
        #pragma unroll
        for (int q = 0; q < 4; ++q) {
            pm[r][q] = (double)psMatrix[r * 4 + q];
            s += pm[r][q];
        }
        pm[r][r] += (1.0 - s);
    }

    double st[4];
    #pragma unroll
    for (int r = 0; r < 4; ++r)
        st[r] = (double)state[(size_t)b * 4 * NN + r * NN + j];

    const double S = st[0];
    const double ps10[4] = {1.0 - ps1, ps1, 0.0, 0.0};

    double P[4];
    #pragma unroll
    for (int i = 0; i < 4; ++i) {
        double acc = S * ps10[i];
        #pragma unroll
        for (int r = 1; r < 4; ++r)
            acc += pm[r][i] * st[r];
        P[i] = acc;
    }

    double u = (double)U[j];
    #pragma unroll
    for (int i = 0; i < 4; ++i) {
        u -= P[i];
        const double s = (u < 0.0) ? 1.0 : 0.0;
        out[(size_t)b * 4 * NN + i * NN + j] = (float)s;
        u += s;
    }
}

// ---------- Fallback (verbatim round-6 kernel, used only if ws too small) ----------
__global__ __launch_bounds__(256, 4) void epi_fallback(
    const float* __restrict__ state, const float* __restrict__ ISNet,
    const float* __restrict__ psMatrix, const float* __restrict__ U,
    float* __restrict__ out)
{
    const int j0 = blockIdx.x * JT;
    const int tid = threadIdx.x;
    const int wave = tid >> 6, lane = tid & 63;
    const int b0 = wave * 2;
    const float p01 = psMatrix[1];
    float cf[JT][2]; double prod[JT][2];
    #pragma unroll
    for (int jj = 0; jj < JT; ++jj)
        #pragma unroll
        for (int bi = 0; bi < 2; ++bi) {
            cf[jj][bi] = state[(size_t)(b0 + bi) * 4 * NN + (j0 + jj)] * p01;
            prod[jj][bi] = 1.0;
        }
    const float4* __restrict__ w0 = (const float4*)(ISNet + (size_t)(j0 + 0) * NN);
    const float4* __restrict__ w1 = (const float4*)(ISNet + (size_t)(j0 + 1) * NN);
    const float4* __restrict__ w2 = (const float4*)(ISNet + (size_t)(j0 + 2) * NN);
    const float4* __restrict__ w3 = (const float4*)(ISNet + (size_t)(j0 + 3) * NN);
    const float4* __restrict__ i0 = (const float4*)(state + ((size_t)(b0 + 0) * 4 + 2) * NN);
    const float4* __restrict__ i1 = (const float4*)(state + ((size_t)(b0 + 1) * 4 + 2) * NN);
    float4 wA[JT], wB[JT], wC[JT], ia[2], ib[2];
#define LW(BUF, IDX) do { const int _x = lane + (IDX) * 64; \
        BUF[0] = w0[_x]; BUF[1] = w1[_x]; BUF[2] = w2[_x]; BUF[3] = w3[_x]; } while (0)
#define LI(BUF, IDX) do { const int _x = lane + (IDX) * 64; \
        BUF[0] = i0[_x]; BUF[1] = i1[_x]; } while (0)
    auto compute = [&](const float4 (&W)[JT], const float4 (&I)[2]) {
        #pragma unroll
        for (int jj = 0; jj < JT; ++jj) {
            const float2 w01 = make_float2(W[jj].x, W[jj].y);
            const float2 w23 = make_float2(W[jj].z, W[jj].w);
            #pragma unroll
            for (int bi = 0; bi < 2; ++bi) {
                const float4& I4 = bi ? I[1] : I[0];
                const float2 c2 = make_float2(cf[jj][bi], cf[jj][bi]);
                const float2 z01 = pk_mul(pk_mul(c2, w01), make_float2(I4.x, I4.y));
                const float2 z23 = pk_mul(pk_mul(c2, w23), make_float2(I4.z, I4.w));
                const float2 q2 = pk_fnma(z01, z23, pk_add(z01, z23));
                const float q = fmaf(-q2.x, q2.y, q2.x + q2.y);
                prod[jj][bi] = fma(-(double)q, prod[jj][bi], prod[jj][bi]);
            }
        }
    };
#define STEP(W, I, K) do { compute(W, I); \
        if ((K) + 3 < 16) LW(W, (K) + 3); if ((K) + 2 < 16) LI(I, (K) + 2); } while (0)
    LW(wA, 0); LI(ia, 0); LW(wB, 1); LI(ib, 1); LW(wC, 2);
    STEP(wA, ia, 0);  STEP(wB, ib, 1);  STEP(wC, ia, 2);  STEP(wA, ib, 3);
    STEP(wB, ia, 4);  STEP(wC, ib, 5);  STEP(wA, ia, 6);  STEP(wB, ib, 7);
    STEP(wC, ia, 8);  STEP(wA, ib, 9);  STEP(wB, ia, 10); STEP(wC, ib, 11);
    STEP(wA, ia, 12); STEP(wB, ib, 13); STEP(wC, ia, 14); STEP(wA, ib, 15);
#undef STEP
#undef LW
#undef LI
    #pragma unroll
    for (int off = 32; off >= 8; off >>= 1)
        #pragma unroll
        for (int jj = 0; jj < JT; ++jj)
            #pragma unroll
            for (int bi = 0; bi < 2; ++bi)
                prod[jj][bi] *= __shfl_xor(prod[jj][bi], off, 64);
    const int g = lane >> 3;
    double v = prod[0][0];
    v = (g == 1) ? prod[0][1] : v; v = (g == 2) ? prod[1][0] : v;
    v = (g == 3) ? prod[1][1] : v; v = (g == 4) ? prod[2][0] : v;
    v = (g == 5) ? prod[2][1] : v; v = (g == 6) ? prod[3][0] : v;
    v = (g == 7) ? prod[3][1] : v;
    v *= __shfl_down(v, 4, 64); v *= __shfl_down(v, 2, 64); v *= __shfl_down(v, 1, 64);
    __shared__ double red[JT][BB];
    if ((lane & 7) == 0) red[g >> 1][b0 + (g & 1)] = v;
    __syncthreads();
    if (tid < JT * BB) {
        const int jj = tid >> 3, b = tid & 7;
        const int j = j0 + jj;
        const double ps1 = 1.0 - red[jj][b];
        double pm[4][4];
        #pragma unroll
        for (int r = 0; r < 4; ++r) {
            double s = 0.0;
            #pragma unroll
            for (int q = 0; q < 4; ++q) { pm[r][q] = (double)psMatrix[r * 4 + q]; s += pm[r][q]; }
            pm[r][r] += (1.0 - s);
        }
        double st[4];
        #pragma unroll
        for (int r = 0; r < 4; ++r) st[r] = (double)state[(size_t)b * 4 * NN + r * NN + j];
        const double S = st[0];
        const double ps10[4] = {1.0 - ps1, ps1, 0.0, 0.0};
        double P[4];
        #pragma unroll
        for (int i = 0; i < 4; ++i) {
            double acc = S * ps10[i];
            #pragma unroll
            for (int r = 1; r < 4; ++r) acc += pm[r][i] * st[r];
            P[i] = acc;
        }
        double u = (double)U[j];
        #pragma unroll
        for (int i = 0; i < 4; ++i) {
            u -= P[i];
            const double s = (u < 0.0) ? 1.0 : 0.0;
            out[(size_t)b * 4 * NN + i * NN + j] = (float)s;
            u += s;
        }
    }
}

extern "C" void kernel_launch(void* const* d_in, const int* in_sizes, int n_in,
                              void* d_out, int out_size, void* d_ws, size_t ws_size,
                              hipStream_t stream) {
    const float* state    = (const float*)d_in[0];  // [8,4,4096]
    const float* ISNet    = (const float*)d_in[1];  // [4096,4096]
    const float* psMatrix = (const float*)d_in[2];  // [4,4]
    const float* U        = (const float*)d_in[3];  // [4096]
    float* out            = (float*)d_out;          // [8,4,4096]

    const size_t need = (size_t)KS * BB * NN * sizeof(double);  // 512 KB
    if (ws_size >= need) {
        double* ws = (double*)d_ws;
        epi_partial<<<(NN / JT) * KS, 256, 0, stream>>>(state, ISNet, psMatrix, ws);
        epi_combine<<<(BB * NN) / 256, 256, 0, stream>>>(state, psMatrix, U, ws, out);
    } else {
        epi_fallback<<<NN / JT, 256, 0, stream>>>(state, ISNet, psMatrix, U, out);
    }
}